// Round 1
// baseline (1533.720 us; speedup 1.0000x reference)
//
#include <hip/hip_runtime.h>
#include <hip/hip_bf16.h>
#include <cstdint>

#define NPB 32   // nodes per block in the fused linear kernel

// Kernel 1: out = x@W_skip + b_skip ; k = x@W_key + b_key ; qv[interleaved] = {x@W_query + b_query, x@W_value + b_value}
__global__ __launch_bounds__(256) void fused_linear_kernel(
    const float* __restrict__ x,
    const float* __restrict__ Wk, const float* __restrict__ bk,
    const float* __restrict__ Wq, const float* __restrict__ bq,
    const float* __restrict__ Wv, const float* __restrict__ bv,
    const float* __restrict__ Ws, const float* __restrict__ bs,
    float* __restrict__ karr, float* __restrict__ qvarr,
    float* __restrict__ out, int N)
{
    __shared__ float sW[4][64][64];   // 64 KiB
    __shared__ float sb[4][64];
    __shared__ float sx[NPB][64];     // 8 KiB

    const int tid = threadIdx.x;

    const float* Wsrc[4] = {Wk, Wq, Wv, Ws};
    const float* bsrc[4] = {bk, bq, bv, bs};
    #pragma unroll
    for (int m = 0; m < 4; ++m) {
        const float4* src = (const float4*)Wsrc[m];
        float4* dstp = (float4*)&sW[m][0][0];
        for (int i = tid; i < 1024; i += 256) dstp[i] = src[i];
        if (tid < 64) sb[m][tid] = bsrc[m][tid];
    }

    const int node0 = blockIdx.x * NPB;
    {
        const float4* xs = (const float4*)(x + (size_t)node0 * 64);
        float4* xd = (float4*)&sx[0][0];
        int cnt = NPB * 16;                       // float4 count
        int maxv = (N - node0) * 16;              // valid float4s
        if (maxv > cnt) maxv = cnt;
        for (int i = tid; i < cnt; i += 256)
            xd[i] = (i < maxv) ? xs[i] : float4{0.f, 0.f, 0.f, 0.f};
    }
    __syncthreads();

    const int w = tid >> 6;      // wave id 0..3
    const int l = tid & 63;      // output feature
    const int nbase = w * 8;     // first node (within block) for this wave

    float acc[8][4];
    #pragma unroll
    for (int r = 0; r < 8; ++r)
        #pragma unroll
        for (int m = 0; m < 4; ++m) acc[r][m] = 0.f;

    #pragma unroll 16
    for (int i = 0; i < 64; ++i) {
        float wv4[4];
        #pragma unroll
        for (int m = 0; m < 4; ++m) wv4[m] = sW[m][i][l];
        #pragma unroll
        for (int r = 0; r < 8; ++r) {
            float xb = sx[nbase + r][i];
            #pragma unroll
            for (int m = 0; m < 4; ++m) acc[r][m] = fmaf(xb, wv4[m], acc[r][m]);
        }
    }

    #pragma unroll
    for (int r = 0; r < 8; ++r) {
        int node = node0 + nbase + r;
        if (node < N) {
            karr[(size_t)node * 64 + l]         = acc[r][0] + sb[0][l];
            qvarr[(size_t)node * 128 + l]       = acc[r][1] + sb[1][l];
            qvarr[(size_t)node * 128 + 64 + l]  = acc[r][2] + sb[2][l];
            out[(size_t)node * 64 + l]          = acc[r][3] + sb[3][l];
        }
    }
}

// Kernel 2: per edge e: out[dst] += sigmoid(k[dst] + q[src]) * v[src]
// 16 threads per edge, one float4 per thread.
__global__ __launch_bounds__(256) void edge_kernel(
    const int* __restrict__ esrc, const int* __restrict__ edst,
    const float* __restrict__ karr, const float* __restrict__ qvarr,
    float* __restrict__ out, int E)
{
    int gid = blockIdx.x * 256 + threadIdx.x;
    int e = gid >> 4;
    if (e >= E) return;
    int f = (gid & 15) << 2;

    int s = esrc[e];
    int d = edst[e];

    const float4 kd = *(const float4*)(karr + (size_t)d * 64 + f);
    const float4 qs = *(const float4*)(qvarr + (size_t)s * 128 + f);
    const float4 vs = *(const float4*)(qvarr + (size_t)s * 128 + 64 + f);

    float4 m;
    m.x = vs.x / (1.f + __expf(-(kd.x + qs.x)));
    m.y = vs.y / (1.f + __expf(-(kd.y + qs.y)));
    m.z = vs.z / (1.f + __expf(-(kd.z + qs.z)));
    m.w = vs.w / (1.f + __expf(-(kd.w + qs.w)));

    float* o = out + (size_t)d * 64 + f;
    unsafeAtomicAdd(o + 0, m.x);
    unsafeAtomicAdd(o + 1, m.y);
    unsafeAtomicAdd(o + 2, m.z);
    unsafeAtomicAdd(o + 3, m.w);
}

extern "C" void kernel_launch(void* const* d_in, const int* in_sizes, int n_in,
                              void* d_out, int out_size, void* d_ws, size_t ws_size,
                              hipStream_t stream) {
    const float* x  = (const float*)d_in[0];
    const int* edge = (const int*)d_in[1];
    const float* Wk = (const float*)d_in[2];
    const float* bk = (const float*)d_in[3];
    const float* Wq = (const float*)d_in[4];
    const float* bq = (const float*)d_in[5];
    const float* Wv = (const float*)d_in[6];
    const float* bv = (const float*)d_in[7];
    const float* Ws = (const float*)d_in[8];
    const float* bs = (const float*)d_in[9];
    float* out = (float*)d_out;

    const int N = in_sizes[0] / 64;
    const int E = in_sizes[1] / 2;
    const int* esrc = edge;       // edge_index[0] = source j
    const int* edst = edge + E;   // edge_index[1] = target i

    float* karr  = (float*)d_ws;                 // N*64 floats
    float* qvarr = karr + (size_t)N * 64;        // N*128 floats (q|v interleaved)

    const int nblocks1 = (N + NPB - 1) / NPB;
    fused_linear_kernel<<<nblocks1, 256, 0, stream>>>(
        x, Wk, bk, Wq, bq, Wv, bv, Ws, bs, karr, qvarr, out, N);

    const long long tot = (long long)E * 16;
    const int nblocks2 = (int)((tot + 255) / 256);
    edge_kernel<<<nblocks2, 256, 0, stream>>>(esrc, edst, karr, qvarr, out, E);
}

// Round 2
// 477.269 us; speedup vs baseline: 3.2135x; 3.2135x over previous
//
#include <hip/hip_runtime.h>
#include <hip/hip_bf16.h>
#include <cstdint>

#define NPB 32   // nodes per block in the fused linear kernel

// ---------------------------------------------------------------------------
// Kernel 1: out = x@W_skip + b_skip ; k = x@W_key + b_key ;
//           qv[interleaved 128-stride] = {x@W_query + b_query, x@W_value + b_value}
// ---------------------------------------------------------------------------
__global__ __launch_bounds__(256) void fused_linear_kernel(
    const float* __restrict__ x,
    const float* __restrict__ Wk, const float* __restrict__ bk,
    const float* __restrict__ Wq, const float* __restrict__ bq,
    const float* __restrict__ Wv, const float* __restrict__ bv,
    const float* __restrict__ Ws, const float* __restrict__ bs,
    float* __restrict__ karr, float* __restrict__ qvarr,
    float* __restrict__ out, int N)
{
    __shared__ float sW[4][64][64];   // 64 KiB
    __shared__ float sb[4][64];
    __shared__ float sx[NPB][64];     // 8 KiB

    const int tid = threadIdx.x;

    const float* Wsrc[4] = {Wk, Wq, Wv, Ws};
    const float* bsrc[4] = {bk, bq, bv, bs};
    #pragma unroll
    for (int m = 0; m < 4; ++m) {
        const float4* src = (const float4*)Wsrc[m];
        float4* dstp = (float4*)&sW[m][0][0];
        for (int i = tid; i < 1024; i += 256) dstp[i] = src[i];
        if (tid < 64) sb[m][tid] = bsrc[m][tid];
    }

    const int node0 = blockIdx.x * NPB;
    {
        const float4* xs = (const float4*)(x + (size_t)node0 * 64);
        float4* xd = (float4*)&sx[0][0];
        int cnt = NPB * 16;                       // float4 count
        int maxv = (N - node0) * 16;              // valid float4s
        if (maxv > cnt) maxv = cnt;
        for (int i = tid; i < cnt; i += 256)
            xd[i] = (i < maxv) ? xs[i] : float4{0.f, 0.f, 0.f, 0.f};
    }
    __syncthreads();

    const int w = tid >> 6;      // wave id 0..3
    const int l = tid & 63;      // output feature
    const int nbase = w * 8;     // first node (within block) for this wave

    float acc[8][4];
    #pragma unroll
    for (int r = 0; r < 8; ++r)
        #pragma unroll
        for (int m = 0; m < 4; ++m) acc[r][m] = 0.f;

    #pragma unroll 16
    for (int i = 0; i < 64; ++i) {
        float wv4[4];
        #pragma unroll
        for (int m = 0; m < 4; ++m) wv4[m] = sW[m][i][l];
        #pragma unroll
        for (int r = 0; r < 8; ++r) {
            float xb = sx[nbase + r][i];
            #pragma unroll
            for (int m = 0; m < 4; ++m) acc[r][m] = fmaf(xb, wv4[m], acc[r][m]);
        }
    }

    #pragma unroll
    for (int r = 0; r < 8; ++r) {
        int node = node0 + nbase + r;
        if (node < N) {
            karr[(size_t)node * 64 + l]         = acc[r][0] + sb[0][l];
            qvarr[(size_t)node * 128 + l]       = acc[r][1] + sb[1][l];
            qvarr[(size_t)node * 128 + 64 + l]  = acc[r][2] + sb[2][l];
            out[(size_t)node * 64 + l]          = acc[r][3] + sb[3][l];
        }
    }
}

// ---------------------------------------------------------------------------
// CSR construction: histogram -> exclusive scan -> stable-ish scatter
// ---------------------------------------------------------------------------
__global__ __launch_bounds__(256) void hist_kernel(
    const int* __restrict__ edst, int* __restrict__ counts, int E)
{
    int e = blockIdx.x * 256 + threadIdx.x;
    if (e < E) atomicAdd(&counts[edst[e]], 1);
}

// scan_a: per-chunk (2048 elems) exclusive scan of counts -> offsets (chunk-local),
//         chunk total -> blocksums[chunk]
__global__ __launch_bounds__(256) void scan_a(
    const int* __restrict__ counts, int* __restrict__ offsets,
    int* __restrict__ blocksums, int N)
{
    __shared__ int lds[256];
    const int t = threadIdx.x, b = blockIdx.x;
    const int base = b * 2048 + t * 8;
    int v[8]; int T = 0;
    #pragma unroll
    for (int j = 0; j < 8; ++j) {
        v[j] = (base + j < N) ? counts[base + j] : 0;
        T += v[j];
    }
    lds[t] = T;
    __syncthreads();
    for (int d = 1; d < 256; d <<= 1) {
        int xv = (t >= d) ? lds[t - d] : 0;
        __syncthreads();
        lds[t] += xv;
        __syncthreads();
    }
    int excl = lds[t] - T;
    if (t == 255) blocksums[b] = lds[255];
    int run = excl;
    #pragma unroll
    for (int j = 0; j < 8; ++j) {
        if (base + j < N) offsets[base + j] = run;
        run += v[j];
    }
}

// scan_b: exclusive scan of blocksums (nchunks <= 64) in one block
__global__ __launch_bounds__(64) void scan_b(int* __restrict__ blocksums, int nchunks)
{
    __shared__ int lds[64];
    const int t = threadIdx.x;
    int v = (t < nchunks) ? blocksums[t] : 0;
    lds[t] = v;
    __syncthreads();
    for (int d = 1; d < 64; d <<= 1) {
        int xv = (t >= d) ? lds[t - d] : 0;
        __syncthreads();
        lds[t] += xv;
        __syncthreads();
    }
    if (t < nchunks) blocksums[t] = lds[t] - v;   // exclusive
}

// scan_c: add chunk base; duplicate into cursor; set offsets[N] = E
__global__ __launch_bounds__(256) void scan_c(
    int* __restrict__ offsets, int* __restrict__ cursor,
    const int* __restrict__ blocksums, int N, int E)
{
    const int t = threadIdx.x, b = blockIdx.x;
    const int add = blocksums[b];
    const int base = b * 2048 + t * 8;
    #pragma unroll
    for (int j = 0; j < 8; ++j) {
        int i = base + j;
        if (i < N) {
            int o = offsets[i] + add;
            offsets[i] = o;
            cursor[i]  = o;
        }
    }
    if (b == 0 && t == 0) offsets[N] = E;
}

__global__ __launch_bounds__(256) void scatter_kernel(
    const int* __restrict__ esrc, const int* __restrict__ edst,
    int* __restrict__ cursor, int* __restrict__ ssrc, int E)
{
    int e = blockIdx.x * 256 + threadIdx.x;
    if (e < E) {
        int d = edst[e];
        int p = atomicAdd(&cursor[d], 1);
        ssrc[p] = esrc[e];
    }
}

// ---------------------------------------------------------------------------
// Aggregation: one 64-lane wave per dst node; pull over CSR edge list.
// out[node] += sum_e sigmoid(k[node] + q[src_e]) * v[src_e]
// ---------------------------------------------------------------------------
__global__ __launch_bounds__(256) void agg_kernel(
    const int* __restrict__ offsets, const int* __restrict__ ssrc,
    const float* __restrict__ karr, const float* __restrict__ qvarr,
    float* __restrict__ out, int N)
{
    const int node = blockIdx.x * 4 + (threadIdx.x >> 6);
    if (node >= N) return;
    const int lane = threadIdx.x & 63;

    const int start = offsets[node];
    const int end   = offsets[node + 1];

    const float kv = karr[(size_t)node * 64 + lane];
    float acc = 0.f;

    for (int base = start; base < end; base += 64) {
        const int cnt = min(64, end - base);
        const int sid = (base + lane < end) ? ssrc[base + lane] : 0;
        int i = 0;
        for (; i + 1 < cnt; i += 2) {
            int s0 = __shfl(sid, i);
            int s1 = __shfl(sid, i + 1);
            float q0 = qvarr[(size_t)s0 * 128 + lane];
            float v0 = qvarr[(size_t)s0 * 128 + 64 + lane];
            float q1 = qvarr[(size_t)s1 * 128 + lane];
            float v1 = qvarr[(size_t)s1 * 128 + 64 + lane];
            acc += v0 / (1.f + __expf(-(kv + q0)));
            acc += v1 / (1.f + __expf(-(kv + q1)));
        }
        if (i < cnt) {
            int s0 = __shfl(sid, i);
            float q0 = qvarr[(size_t)s0 * 128 + lane];
            float v0 = qvarr[(size_t)s0 * 128 + 64 + lane];
            acc += v0 / (1.f + __expf(-(kv + q0)));
        }
    }

    out[(size_t)node * 64 + lane] += acc;
}

// ---------------------------------------------------------------------------
extern "C" void kernel_launch(void* const* d_in, const int* in_sizes, int n_in,
                              void* d_out, int out_size, void* d_ws, size_t ws_size,
                              hipStream_t stream) {
    const float* x  = (const float*)d_in[0];
    const int* edge = (const int*)d_in[1];
    const float* Wk = (const float*)d_in[2];
    const float* bk = (const float*)d_in[3];
    const float* Wq = (const float*)d_in[4];
    const float* bq = (const float*)d_in[5];
    const float* Wv = (const float*)d_in[6];
    const float* bv = (const float*)d_in[7];
    const float* Ws = (const float*)d_in[8];
    const float* bs = (const float*)d_in[9];
    float* out = (float*)d_out;

    const int N = in_sizes[0] / 64;
    const int E = in_sizes[1] / 2;
    const int* esrc = edge;       // edge_index[0] = source j
    const int* edst = edge + E;   // edge_index[1] = target i

    // workspace layout
    char* ws = (char*)d_ws;
    float* karr  = (float*)ws;                          ws += (size_t)N * 64 * 4;
    float* qvarr = (float*)ws;                          ws += (size_t)N * 128 * 4;
    int* counts    = (int*)ws;                          ws += (size_t)N * 4;
    int* offsets   = (int*)ws;                          ws += (size_t)(N + 1) * 4;
    int* cursor    = (int*)ws;                          ws += (size_t)N * 4;
    int* blocksums = (int*)ws;                          ws += 64 * 4;
    int* ssrc      = (int*)ws;                          // E ints

    const int nchunks = (N + 2047) / 2048;   // 49 for N=100000 (must be <= 64)

    // zero the histogram counters (stream-ordered, graph-capturable)
    hipMemsetAsync(counts, 0, (size_t)N * 4, stream);

    // 1) fused linear projections
    const int nblocks1 = (N + NPB - 1) / NPB;
    fused_linear_kernel<<<nblocks1, 256, 0, stream>>>(
        x, Wk, bk, Wq, bq, Wv, bv, Ws, bs, karr, qvarr, out, N);

    // 2) CSR build
    const int eblocks = (E + 255) / 256;
    hist_kernel<<<eblocks, 256, 0, stream>>>(edst, counts, E);
    scan_a<<<nchunks, 256, 0, stream>>>(counts, offsets, blocksums, N);
    scan_b<<<1, 64, 0, stream>>>(blocksums, nchunks);
    scan_c<<<nchunks, 256, 0, stream>>>(offsets, cursor, blocksums, N, E);
    scatter_kernel<<<eblocks, 256, 0, stream>>>(esrc, edst, cursor, ssrc, E);

    // 3) pull aggregation
    const int ablocks = (N + 3) / 4;
    agg_kernel<<<ablocks, 256, 0, stream>>>(offsets, ssrc, karr, qvarr, out, N);
}